// Round 15
// baseline (239.965 us; speedup 1.0000x reference)
//
#include <hip/hip_runtime.h>
#include <cstdint>

// Problem constants
#define T_DIM 8192
#define D_DIM 1024
#define NB_DIM 64
#define QKS 2048  // row stride of fused q|k buffer

typedef __bf16 bf16x8 __attribute__((ext_vector_type(8)));
typedef __bf16 bf16x4 __attribute__((ext_vector_type(4)));
typedef float f32x4 __attribute__((ext_vector_type(4)));

#define MFMA16(a, b, c) __builtin_amdgcn_mfma_f32_16x16x32_bf16((a), (b), (c), 0, 0, 0)
#define BAR() asm volatile("s_barrier" ::: "memory")
#define VMCNT(n) asm volatile("s_waitcnt vmcnt(" #n ")" ::: "memory")

// async global->LDS, 16B per lane. LDS dest must be wave-uniform base + lane*16.
__device__ __forceinline__ void gld_lds16(const void* gsrc, void* ldst) {
  __builtin_amdgcn_global_load_lds(
      (__attribute__((address_space(1))) void*)(uintptr_t)gsrc,
      (__attribute__((address_space(3))) void*)(uintptr_t)ldst,
      16, 0, 0);
}

// ---------------------------------------------------------------------------
// Batched weight convert+transpose: 6 jobs in ONE launch (8192 blocks).
// ---------------------------------------------------------------------------
__global__ __launch_bounds__(256) void transpose_all(
    const float* __restrict__ wq, const float* __restrict__ wk,
    const float* __restrict__ wv, const float* __restrict__ wo,
    const float* __restrict__ wg, const float* __restrict__ wd,
    __bf16* __restrict__ wqkT, __bf16* __restrict__ wvT,
    __bf16* __restrict__ woT, __bf16* __restrict__ wgT,
    __bf16* __restrict__ wdT) {
  __shared__ float tile[32][33];
  const int bid = (int)blockIdx.x;
  const float* W; __bf16* Wt; int K, N, n0, k0, local;
  if (bid < 1024)      { W = wq; Wt = wqkT;            K = 1024; N = 1024; local = bid; }
  else if (bid < 2048) { W = wk; Wt = wqkT + 1048576;  K = 1024; N = 1024; local = bid - 1024; }
  else if (bid < 3072) { W = wv; Wt = wvT;             K = 1024; N = 1024; local = bid - 2048; }
  else if (bid < 4096) { W = wo; Wt = woT;             K = 1024; N = 1024; local = bid - 3072; }
  else if (bid < 6144) { W = wg; Wt = wgT;             K = 1024; N = 2048; local = bid - 4096; }
  else                 { W = wd; Wt = wdT;             K = 2048; N = 1024; local = bid - 6144; }
  if (N == 2048) { n0 = (local & 63) * 32; k0 = (local >> 6) * 32; }
  else           { n0 = (local & 31) * 32; k0 = (local >> 5) * 32; }
  const int tx = threadIdx.x & 31, ty = threadIdx.x >> 5;
#pragma unroll
  for (int i = 0; i < 32; i += 8)
    tile[ty + i][tx] = W[(size_t)(k0 + ty + i) * N + n0 + tx];
  __syncthreads();
#pragma unroll
  for (int i = 0; i < 32; i += 8)
    Wt[(size_t)(n0 + ty + i) * K + k0 + tx] = (__bf16)tile[tx][ty + i];
}

// ---------------------------------------------------------------------------
// LayerNorm: x[row][1024] (f32 or bf16) -> out bf16. One block (256) per row.
// ---------------------------------------------------------------------------
template <typename TI>
__global__ __launch_bounds__(256) void ln_kernel(
    const TI* __restrict__ x, const float* __restrict__ g,
    const float* __restrict__ b, __bf16* __restrict__ out) {
  __shared__ float red[8];
  const int row = blockIdx.x, tid = threadIdx.x;
  float v0, v1, v2, v3;
  if constexpr (sizeof(TI) == 4) {
    const float4 v = ((const float4*)(x + (size_t)row * D_DIM))[tid];
    v0 = v.x; v1 = v.y; v2 = v.z; v3 = v.w;
  } else {
    const bf16x4 v = ((const bf16x4*)(x + (size_t)row * D_DIM))[tid];
    v0 = (float)v[0]; v1 = (float)v[1]; v2 = (float)v[2]; v3 = (float)v[3];
  }
  float s = v0 + v1 + v2 + v3;
#pragma unroll
  for (int off = 32; off >= 1; off >>= 1) s += __shfl_xor(s, off, 64);
  if ((tid & 63) == 0) red[tid >> 6] = s;
  __syncthreads();
  const float mean = (red[0] + red[1] + red[2] + red[3]) * (1.0f / D_DIM);
  const float d0 = v0 - mean, d1 = v1 - mean, d2 = v2 - mean, d3 = v3 - mean;
  float ss = d0 * d0 + d1 * d1 + d2 * d2 + d3 * d3;
#pragma unroll
  for (int off = 32; off >= 1; off >>= 1) ss += __shfl_xor(ss, off, 64);
  if ((tid & 63) == 0) red[4 + (tid >> 6)] = ss;
  __syncthreads();
  const float var = (red[4] + red[5] + red[6] + red[7]) * (1.0f / D_DIM);
  const float rstd = rsqrtf(var + 1e-5f);
  const float4 gg = ((const float4*)g)[tid];
  const float4 bb = ((const float4*)b)[tid];
  bf16x4 o;
  o[0] = (__bf16)(d0 * rstd * gg.x + bb.x);
  o[1] = (__bf16)(d1 * rstd * gg.y + bb.y);
  o[2] = (__bf16)(d2 * rstd * gg.z + bb.z);
  o[3] = (__bf16)(d3 * rstd * gg.w + bb.w);
  *(bf16x4*)(out + (size_t)row * D_DIM + tid * 4) = o;
}

// ---------------------------------------------------------------------------
// gemm_hi — HIGH-OCCUPANCY GEMM: BM=128, BN=128, BK=64, 512 thr = 8 waves
// (2M x 4N, wave = 64x32, acc 4x2). Double-buffered LDS = 64 KB exactly ->
// 2 blocks/CU, 4 waves/SIMD (vs gemm8's 1 block / 2 waves). Latency hiding
// via TLP (m114) instead of schedule. Simple 2-phase loop, T2 XOR swizzle.
// C[M][N] = A[M][K] * Bt[N][K]^T.  EPI: 0 bf16; 3 silu->bf16.
// ---------------------------------------------------------------------------
template <int EPI>
__global__ __launch_bounds__(512, 4) void gemm_hi(
    const __bf16* __restrict__ A, const __bf16* __restrict__ Bt,
    void* __restrict__ Cout, int M, int N, int K, int nbn) {
  __shared__ __bf16 lds[2][16384];  // per buf: A[128*64] | B[128*64]
  const int tid = threadIdx.x;
  const int l = tid & 63, w = tid >> 6;
  const int lr = l & 15, lg = l >> 4;
  const int wr = w >> 2, wc = w & 3;  // 2M x 4N waves
  const int nwg = gridDim.x;
  const int bid = (int)blockIdx.x;
  const int swz = (bid & 7) * (nwg >> 3) + (bid >> 3);
  const int bm = swz / nbn, bn = swz % nbn;
  const int am0 = bm * 128, bn0 = bn * 128;

  f32x4 acc[4][2];
  const f32x4 z4 = {0.f, 0.f, 0.f, 0.f};
#pragma unroll
  for (int m = 0; m < 4; ++m)
#pragma unroll
    for (int n = 0; n < 2; ++n) acc[m][n] = z4;

  auto stage = [&](int b, int k0) {
#pragma unroll
    for (int r = 0; r < 2; ++r) {
      const int ci = r * 512 + tid;
      const int row = ci >> 3, c8 = ci & 7;
      gld_lds16(A + (size_t)(am0 + row) * K + k0 + ((c8 ^ (row & 7)) << 3),
                &lds[b][ci * 8]);
      gld_lds16(Bt + (size_t)(bn0 + row) * K + k0 + ((c8 ^ (row & 7)) << 3),
                &lds[b][8192 + ci * 8]);
    }
  };

  const int nt = K >> 6;
  stage(0, 0);
  __syncthreads();  // drains vmcnt(0)

  int cur = 0;
  for (int t = 0; t < nt; ++t) {
    if (t + 1 < nt) stage(cur ^ 1, (t + 1) << 6);
#pragma unroll
    for (int kk = 0; kk < 2; ++kk) {
      bf16x8 af[4], bf_[2];
#pragma unroll
      for (int m = 0; m < 4; ++m) {
        const int row = wr * 64 + m * 16 + lr;
        af[m] = *(const bf16x8*)&lds[cur][row * 64 + (((kk * 4 + lg) ^ (row & 7)) << 3)];
      }
#pragma unroll
      for (int n = 0; n < 2; ++n) {
        const int row = wc * 32 + n * 16 + lr;
        bf_[n] = *(const bf16x8*)&lds[cur][8192 + row * 64 + (((kk * 4 + lg) ^ (row & 7)) << 3)];
      }
      __builtin_amdgcn_s_setprio(1);
#pragma unroll
      for (int m = 0; m < 4; ++m)
#pragma unroll
        for (int n = 0; n < 2; ++n) acc[m][n] = MFMA16(af[m], bf_[n], acc[m][n]);
      __builtin_amdgcn_s_setprio(0);
    }
    __syncthreads();  // staging complete + reads of cur done
    cur ^= 1;
  }

  // ---- epilogue: C/D frag col = lane&15, row = (lane>>4)*4 + reg ----
  // Stage tile through LDS (chunk-swizzled) -> 16B coalesced stores.
  __bf16* Ct = (__bf16*)lds;  // 128*128*2 = 32 KB
#pragma unroll
  for (int mf = 0; mf < 4; ++mf)
#pragma unroll
    for (int nf = 0; nf < 2; ++nf)
#pragma unroll
      for (int r = 0; r < 4; ++r) {
        const int rl = wr * 64 + mf * 16 + lg * 4 + r;
        const int cl = wc * 32 + nf * 16 + lr;
        float v = acc[mf][nf][r];
        if constexpr (EPI == 3) v = v / (1.f + __expf(-v));
        Ct[rl * 128 + (((cl >> 3) ^ (rl & 7)) << 3) + (cl & 7)] = (__bf16)v;
      }
  __syncthreads();
  __bf16* O = (__bf16*)Cout;
#pragma unroll
  for (int i = 0; i < 4; ++i) {
    const int ci = i * 512 + tid;
    const int row = ci >> 4, c8 = ci & 15;
    *(bf16x8*)(O + (size_t)(am0 + row) * N + bn0 + c8 * 8) =
        *(const bf16x8*)&Ct[row * 128 + ((c8 ^ (row & 7)) << 3)];
  }
}

// ---------------------------------------------------------------------------
// gemm8 (R10-verified) — kept for residual EPIs (wo, down). BM=128.
// ---------------------------------------------------------------------------
template <int BM_, int EPI>
__global__ __launch_bounds__(512, 2) void gemm8(
    const __bf16* __restrict__ A, const __bf16* __restrict__ Bt,
    const void* __restrict__ Res, void* __restrict__ Cout,
    int M, int N, int K, int nbn) {
  constexpr int MF = BM_ / 32;
  constexpr int MH = MF / 2;
  constexpr int SA = 8 * MF;
  constexpr int LA = BM_ / 128;
  constexpr int ATILE = BM_ * 64;
  constexpr int AHALF = BM_ * 32;
  constexpr int BOFF = 2 * ATILE;
  __shared__ __bf16 lds[2 * BM_ * 64 + 32768];

  const int tid = threadIdx.x;
  const int l = tid & 63, w = tid >> 6;
  const int lr = l & 15, lg = l >> 4;
  const int wr = w >> 2, wc = w & 3;
  const int nwg = gridDim.x;
  const int bid = (int)blockIdx.x;
  const int swz = (bid & 7) * (nwg >> 3) + (bid >> 3);
  const int bm = swz / nbn, bn = swz % nbn;
  const int am0 = bm * BM_, bn0 = bn * 256;

  f32x4 acc[MF][4];
  const f32x4 z4 = {0.f, 0.f, 0.f, 0.f};
#pragma unroll
  for (int m = 0; m < MF; ++m)
#pragma unroll
    for (int n = 0; n < 4; ++n) acc[m][n] = z4;

  auto stageA = [&](int h, int b, int k0) {
#pragma unroll
    for (int r = 0; r < LA; ++r) {
      const int ci = r * 512 + tid;
      const int wri = ci >> 3, c8 = ci & 7;
      const int ra = (wri % SA) + (wri / SA) * (2 * SA) + h * SA;
      gld_lds16(A + (size_t)(am0 + ra) * K + k0 + ((c8 ^ (wri & 7)) << 3),
                (__bf16*)lds + b * ATILE + h * AHALF + ci * 8);
    }
  };
  auto stageB = [&](int h, int b, int k0) {
#pragma unroll
    for (int r = 0; r < 2; ++r) {
      const int ci = r * 512 + tid;
      const int wri = ci >> 3, c8 = ci & 7;
      const int rb = (wri & 31) + (wri >> 5) * 64 + h * 32;
      gld_lds16(Bt + (size_t)(bn0 + rb) * K + k0 + ((c8 ^ (wri & 7)) << 3),
                (__bf16*)lds + BOFF + b * 16384 + h * 8192 + ci * 8);
    }
  };

  const int x7 = lr & 7;
  const int aoff0 = (lr + wr * SA) * 64 + ((lg) ^ x7) * 8;
  const int aoff1 = (lr + wr * SA) * 64 + ((4 + lg) ^ x7) * 8;
  const int boff0 = BOFF + (lr + wc * 32) * 64 + ((lg) ^ x7) * 8;
  const int boff1 = BOFF + (lr + wc * 32) * 64 + ((4 + lg) ^ x7) * 8;

  const int nt = K >> 6;
  stageA(0, 0, 0);
  stageB(1, 0, 0);
  stageB(0, 0, 0);
  stageA(1, 0, 0);
  stageA(0, 1, 64);
  stageB(1, 1, 64);
  if constexpr (BM_ == 256) VMCNT(6); else VMCNT(4);
  BAR();

  int buf = 0;
  bf16x8 afr[MH][2], bfr0[2][2], bfr1[2][2];
  for (int t = 0; t < nt; ++t) {
    const bool s1 = (t + 1 < nt);
    const bool s2 = (t + 2 < nt);
    const int nb = buf ^ 1;
    const int k1 = (t + 1) << 6;
    const int k2 = (t + 2) << 6;
    const __bf16* pa0 = lds + buf * ATILE + aoff0;
    const __bf16* pa1 = lds + buf * ATILE + aoff1;
    const __bf16* pb0 = lds + buf * 16384 + boff0;
    const __bf16* pb1 = lds + buf * 16384 + boff1;

#pragma unroll
    for (int i = 0; i < MH; ++i) {
      afr[i][0] = *(const bf16x8*)(pa0 + i * 1024);
      afr[i][1] = *(const bf16x8*)(pa1 + i * 1024);
    }
#pragma unroll
    for (int j = 0; j < 2; ++j) {
      bfr0[j][0] = *(const bf16x8*)(pb0 + j * 1024);
      bfr0[j][1] = *(const bf16x8*)(pb1 + j * 1024);
    }
    if (s1) stageB(0, nb, k1);
    BAR();
    __builtin_amdgcn_s_setprio(1);
#pragma unroll
    for (int kk = 0; kk < 2; ++kk)
#pragma unroll
      for (int i = 0; i < MH; ++i)
#pragma unroll
        for (int j = 0; j < 2; ++j)
          acc[i][j] = MFMA16(afr[i][kk], bfr0[j][kk], acc[i][j]);
    __builtin_amdgcn_s_setprio(0);

#pragma unroll
    for (int j = 0; j < 2; ++j) {
      bfr1[j][0] = *(const bf16x8*)(pb0 + 8192 + j * 1024);
      bfr1[j][1] = *(const bf16x8*)(pb1 + 8192 + j * 1024);
    }
    if (s1) {
      stageA(1, nb, k1);
      if constexpr (BM_ == 256) VMCNT(8); else VMCNT(6);
    } else {
      VMCNT(0);
    }
    BAR();
    __builtin_amdgcn_s_setprio(1);
#pragma unroll
    for (int kk = 0; kk < 2; ++kk)
#pragma unroll
      for (int i = 0; i < MH; ++i)
#pragma unroll
        for (int j = 0; j < 2; ++j)
          acc[i][2 + j] = MFMA16(afr[i][kk], bfr1[j][kk], acc[i][2 + j]);
    __builtin_amdgcn_s_setprio(0);

#pragma unroll
    for (int i = 0; i < MH; ++i) {
      afr[i][0] = *(const bf16x8*)(pa0 + AHALF + i * 1024);
      afr[i][1] = *(const bf16x8*)(pa1 + AHALF + i * 1024);
    }
    if (s2) stageA(0, buf, k2);
    BAR();
    __builtin_amdgcn_s_setprio(1);
#pragma unroll
    for (int kk = 0; kk < 2; ++kk)
#pragma unroll
      for (int i = 0; i < MH; ++i)
#pragma unroll
        for (int j = 0; j < 2; ++j)
          acc[MH + i][2 + j] = MFMA16(afr[i][kk], bfr1[j][kk], acc[MH + i][2 + j]);
    __builtin_amdgcn_s_setprio(0);

    if (s2) {
      stageB(1, buf, k2);
      if constexpr (BM_ == 256) VMCNT(6); else VMCNT(4);
    } else if (s1) {
      if constexpr (BM_ == 256) VMCNT(2); else VMCNT(1);
    }
    BAR();
    __builtin_amdgcn_s_setprio(1);
#pragma unroll
    for (int kk = 0; kk < 2; ++kk)
#pragma unroll
      for (int i = 0; i < MH; ++i)
#pragma unroll
        for (int j = 0; j < 2; ++j)
          acc[MH + i][j] = MFMA16(afr[i][kk], bfr0[j][kk], acc[MH + i][j]);
    __builtin_amdgcn_s_setprio(0);

    buf = nb;
  }

  if constexpr (EPI == 5) {
    const __bf16* R = (const __bf16*)Res;
    float* O = (float*)Cout;
#pragma unroll
    for (int mf = 0; mf < MF; ++mf)
#pragma unroll
      for (int nf = 0; nf < 4; ++nf)
#pragma unroll
        for (int r = 0; r < 4; ++r) {
          const int row = am0 + wr * 2 * SA + mf * 16 + lg * 4 + r;
          const int col = bn0 + wc * 64 + nf * 16 + lr;
          const size_t idx = (size_t)row * N + col;
          O[idx] = acc[mf][nf][r] + (float)R[idx];
        }
  } else {
    __syncthreads();
    __bf16* Ct = (__bf16*)lds;
#pragma unroll
    for (int mf = 0; mf < MF; ++mf)
#pragma unroll
      for (int nf = 0; nf < 4; ++nf)
#pragma unroll
        for (int r = 0; r < 4; ++r) {
          const int rl = wr * 2 * SA + mf * 16 + lg * 4 + r;
          const int cl = wc * 64 + nf * 16 + lr;
          float v = acc[mf][nf][r];
          if constexpr (EPI == 3) v = v / (1.f + __expf(-v));
          if constexpr (EPI == 4)
            v += ((const float*)Res)[(size_t)(am0 + rl) * N + bn0 + cl];
          Ct[rl * 256 + (((cl >> 3) ^ (rl & 7)) << 3) + (cl & 7)] = (__bf16)v;
        }
    __syncthreads();
    __bf16* O = (__bf16*)Cout;
#pragma unroll
    for (int i = 0; i < BM_ / 16; ++i) {
      const int ci = i * 512 + tid;
      const int row = ci >> 5, c8 = ci & 31;
      *(bf16x8*)(O + (size_t)(am0 + row) * N + bn0 + c8 * 8) =
          *(const bf16x8*)&Ct[row * 256 + ((c8 ^ (row & 7)) << 3)];
    }
  }
}

// ---------------------------------------------------------------------------
// Block-local attention v6 — one wave per block (R14-verified).
// ---------------------------------------------------------------------------
__global__ __launch_bounds__(64, 2) void attn_kernel(
    const __bf16* __restrict__ qk, const __bf16* __restrict__ vT,
    __bf16* __restrict__ out) {
  __shared__ __bf16 Pw[32 * 136];  // 8704 B

  const int l = (int)threadIdx.x;
  const int lr = l & 15, lg = l >> 4;
  const int bx = (int)blockIdx.x;
  const int swz = (bx & 7) * 512 + (bx >> 3);
  const int h = swz >> 8;
  const int blk = (swz >> 2) & 63;
  const int w = swz & 3;

  const __bf16* qbase =
      qk + (size_t)(blk * 128 + w * 32 + lr) * QKS + h * 64 + lg * 8;
  bf16x8 qf[2][2];
#pragma unroll
  for (int m = 0; m < 2; ++m)
#pragma unroll
    for (int ks = 0; ks < 2; ++ks)
      qf[m][ks] = *(const bf16x8*)(qbase + (size_t)m * 16 * QKS + ks * 32);

  const f32x4 z4 = {0.f, 0.f, 0.f, 0.f};
  float ssum[2][4];
  f32x4 o[2][4];
#pragma unroll
  for (int m = 0; m < 2; ++m) {
#pragma unroll
    for (int r = 0; r < 4; ++r) ssum[m][r] = 0.f;
#pragma unroll
    for (int n = 0; n < 4; ++n) o[m][n] = z4;
  }

  for (int it = 0; it < 3; ++it) {
    const int kb = blk + it - 1;
    if (kb < 0 || kb >= NB_DIM) continue;
    const int rel = it - 1;
    const int kclo = (rel < 0) ? (w * 2) : 0;
    const int kchi = (rel > 0) ? (w * 2 + 2) : 8;

    f32x4 s[2][8];
    const __bf16* kbase =
        qk + (size_t)(kb * 128 + lr) * QKS + 1024 + h * 64 + lg * 8;
#pragma unroll
    for (int kc = 0; kc < 8; ++kc) {
      if (kc < kclo || kc >= kchi) continue;
      const bf16x8 k0 = *(const bf16x8*)(kbase + (size_t)kc * 16 * QKS);
      const bf16x8 k1 = *(const bf16x8*)(kbase + (size_t)kc * 16 * QKS + 32);
      s[0][kc] = MFMA16(qf[0][0], k0, z4);
      s[1][kc] = MFMA16(qf[1][0], k0, z4);
      s[0][kc] = MFMA16(qf[0][1], k1, s[0][kc]);
      s[1][kc] = MFMA16(qf[1][1], k1, s[1][kc]);
    }

#pragma unroll
    for (int m = 0; m < 2; ++m) {
#pragma unroll
      for (int r = 0; r < 4; ++r) {
        const int qi = w * 32 + m * 16 + lg * 4 + r;
        float acc_s = 0.f;
#pragma unroll
        for (int kc = 0; kc < 8; ++kc) {
          if (kc < kclo || kc >= kchi) continue;
          const int kj = kc * 16 + lr;
          float p = __expf(s[m][kc][r] * 0.125f);
          const bool valid = (rel == 0) || (rel < 0 ? (kj >= qi) : (kj <= qi));
          p = valid ? p : 0.f;
          s[m][kc][r] = p;
          acc_s += p;
        }
        ssum[m][r] += acc_s;
      }
    }

#pragma unroll
    for (int m = 0; m < 2; ++m)
#pragma unroll
      for (int kc = 0; kc < 8; ++kc) {
        if (kc < kclo || kc >= kchi) continue;
#pragma unroll
        for (int r = 0; r < 4; ++r)
          Pw[(m * 16 + lg * 4 + r) * 136 + kc * 16 + lr] = (__bf16)s[m][kc][r];
      }

    const int kslo = kclo >> 1, kshi = kchi >> 1;
    const __bf16* vbase =
        vT + (size_t)(h * 64 + lr) * T_DIM + kb * 128 + lg * 8;
#pragma unroll
    for (int ks = 0; ks < 4; ++ks) {
      if (ks < kslo || ks >= kshi) continue;
      bf16x8 pa[2];
#pragma unroll
      for (int m = 0; m < 2; ++m)
        pa[m] = *(const bf16x8*)&Pw[(m * 16 + lr) * 136 + ks * 32 + lg * 8];
#pragma unroll
      for (int n = 0; n < 4; ++n) {
        const bf16x8 vb = *(const bf16x8*)(vbase + (size_t)n * 16 * T_DIM + ks * 32);
        o[0][n] = MFMA16(pa[0], vb, o[0][n]);
        o[1][n] = MFMA16(pa[1], vb, o[1][n]);
      }
    }
  }

  float inv[2][4];
#pragma unroll
  for (int m = 0; m < 2; ++m)
#pragma unroll
    for (int r = 0; r < 4; ++r) {
      float rs = ssum[m][r];
#pragma unroll
      for (int off = 1; off < 16; off <<= 1) rs += __shfl_xor(rs, off, 64);
      inv[m][r] = __builtin_amdgcn_rcpf(rs);
    }
#pragma unroll
  for (int m = 0; m < 2; ++m)
#pragma unroll
    for (int n = 0; n < 4; ++n)
#pragma unroll
      for (int r = 0; r < 4; ++r)
        Pw[(m * 16 + lg * 4 + r) * 136 + n * 16 + lr] =
            (__bf16)(o[m][n][r] * inv[m][r]);
#pragma unroll
  for (int i = 0; i < 4; ++i) {
    const int ci = i * 64 + l;
    const int qrow = ci >> 3;
    const int c8 = (ci & 7) * 8;
    const bf16x8 vv = *(const bf16x8*)&Pw[qrow * 136 + c8];
    *(bf16x8*)(out + (size_t)(blk * 128 + w * 32 + qrow) * D_DIM + h * 64 + c8) = vv;
  }
}

// ---------------------------------------------------------------------------
extern "C" void kernel_launch(void* const* d_in, const int* in_sizes, int n_in,
                              void* d_out, int out_size, void* d_ws, size_t ws_size,
                              hipStream_t stream) {
  (void)in_sizes; (void)n_in; (void)out_size; (void)ws_size;
  const float* x      = (const float*)d_in[0];
  const float* wq     = (const float*)d_in[1];
  const float* wk     = (const float*)d_in[2];
  const float* wv     = (const float*)d_in[3];
  const float* wo     = (const float*)d_in[4];
  const float* wg     = (const float*)d_in[5];
  const float* wd     = (const float*)d_in[6];
  const float* norm_g = (const float*)d_in[7];
  const float* norm_b = (const float*)d_in[8];
  const float* ffn_g  = (const float*)d_in[9];
  const float* ffn_b  = (const float*)d_in[10];
  float* out = (float*)d_out;

  // Workspace layout (96 MB used)
  char* ws = (char*)d_ws;
  constexpr size_t MB = 1ull << 20;
  __bf16* wqkT = (__bf16*)(ws + 0 * MB);    // [2048][1024]
  __bf16* wvT  = (__bf16*)(ws + 4 * MB);    // [1024][1024]
  __bf16* woT  = (__bf16*)(ws + 6 * MB);
  __bf16* wgT  = (__bf16*)(ws + 8 * MB);    // [2048][1024]
  __bf16* wdT  = (__bf16*)(ws + 12 * MB);   // [1024][2048]
  __bf16* hbuf = (__bf16*)(ws + 16 * MB);   // h / attn_out / h2 (16 MB, reused)
  __bf16* qkbf = (__bf16*)(ws + 32 * MB);   // [T][2048] fused q|k (32 MB)
  __bf16* gbf  = (__bf16*)(ws + 32 * MB);   // [T][2048] gate (reuses qk)
  __bf16* vTbf = (__bf16*)(ws + 64 * MB);   // [1024][T] (16 MB)
  __bf16* x2bf = (__bf16*)(ws + 80 * MB);   // [T][D] bf16 residual (16 MB)

  // 1. all weight transposes in ONE launch
  transpose_all<<<8192, 256, 0, stream>>>(wq, wk, wv, wo, wg, wd,
                                          wqkT, wvT, woT, wgT, wdT);

  // 2. LN1 (f32 in)
  ln_kernel<float><<<8192, 256, 0, stream>>>(x, norm_g, norm_b, hbuf);

  // 3. fused Q|K projection (high-occupancy), V^T via swapped-operand gemm_hi
  gemm_hi<0><<<1024, 512, 0, stream>>>(hbuf, wqkT, qkbf, 8192, 2048, 1024, 16);
  gemm_hi<0><<<512, 512, 0, stream>>>(wvT, hbuf, vTbf, 1024, 8192, 1024, 64);

  // 4. local attention -> hbuf (1 wave per block)
  attn_kernel<<<4096, 64, 0, stream>>>(qkbf, vTbf, hbuf);

  // 5. out-proj + residual: x2bf = bf16(x + attn @ wo)
  gemm8<128, 4><<<256, 512, 0, stream>>>(hbuf, woT, x, x2bf, 8192, 1024, 1024, 4);

  // 6. LN2 (bf16 in) -> hbuf
  ln_kernel<__bf16><<<8192, 256, 0, stream>>>(x2bf, ffn_g, ffn_b, hbuf);

  // 7. gate: g = silu(h2 @ wg) (high-occupancy)
  gemm_hi<3><<<1024, 512, 0, stream>>>(hbuf, wgT, gbf, 8192, 2048, 1024, 16);

  // 8. down + residual: out = f32(x2bf + g @ wd)
  gemm8<128, 5><<<256, 512, 0, stream>>>(gbf, wdT, x2bf, out, 8192, 1024, 2048, 4);
}

// Round 16
// 237.376 us; speedup vs baseline: 1.0109x; 1.0109x over previous
//
#include <hip/hip_runtime.h>
#include <cstdint>

// Problem constants
#define T_DIM 8192
#define D_DIM 1024
#define NB_DIM 64
#define QKS 2048  // row stride of fused q|k buffer

typedef __bf16 bf16x8 __attribute__((ext_vector_type(8)));
typedef __bf16 bf16x4 __attribute__((ext_vector_type(4)));
typedef float f32x4 __attribute__((ext_vector_type(4)));

#define MFMA16(a, b, c) __builtin_amdgcn_mfma_f32_16x16x32_bf16((a), (b), (c), 0, 0, 0)
#define BAR() asm volatile("s_barrier" ::: "memory")
#define VMCNT(n) asm volatile("s_waitcnt vmcnt(" #n ")" ::: "memory")

// async global->LDS, 16B per lane. LDS dest must be wave-uniform base + lane*16.
__device__ __forceinline__ void gld_lds16(const void* gsrc, void* ldst) {
  __builtin_amdgcn_global_load_lds(
      (__attribute__((address_space(1))) void*)(uintptr_t)gsrc,
      (__attribute__((address_space(3))) void*)(uintptr_t)ldst,
      16, 0, 0);
}

// ---------------------------------------------------------------------------
// prep_all — weight transposes (6 jobs, blocks 0..8191) + LN1 (blocks
// 8192..16383) in ONE launch: the two are independent; merging fills the
// GPU and removes a launch gap.
// ---------------------------------------------------------------------------
__global__ __launch_bounds__(256) void prep_all(
    const float* __restrict__ wq, const float* __restrict__ wk,
    const float* __restrict__ wv, const float* __restrict__ wo,
    const float* __restrict__ wg, const float* __restrict__ wd,
    __bf16* __restrict__ wqkT, __bf16* __restrict__ wvT,
    __bf16* __restrict__ woT, __bf16* __restrict__ wgT,
    __bf16* __restrict__ wdT,
    const float* __restrict__ x, const float* __restrict__ ng,
    const float* __restrict__ nb, __bf16* __restrict__ h) {
  __shared__ float smem_f[32 * 33];
  const int bid = (int)blockIdx.x;
  const int tid = threadIdx.x;

  if (bid < 8192) {
    // ---- transpose job ----
    float (*tile)[33] = (float(*)[33])smem_f;
    const float* W; __bf16* Wt; int K, N, n0, k0, local;
    if (bid < 1024)      { W = wq; Wt = wqkT;            K = 1024; N = 1024; local = bid; }
    else if (bid < 2048) { W = wk; Wt = wqkT + 1048576;  K = 1024; N = 1024; local = bid - 1024; }
    else if (bid < 3072) { W = wv; Wt = wvT;             K = 1024; N = 1024; local = bid - 2048; }
    else if (bid < 4096) { W = wo; Wt = woT;             K = 1024; N = 1024; local = bid - 3072; }
    else if (bid < 6144) { W = wg; Wt = wgT;             K = 1024; N = 2048; local = bid - 4096; }
    else                 { W = wd; Wt = wdT;             K = 2048; N = 1024; local = bid - 6144; }
    if (N == 2048) { n0 = (local & 63) * 32; k0 = (local >> 6) * 32; }
    else           { n0 = (local & 31) * 32; k0 = (local >> 5) * 32; }
    const int tx = tid & 31, ty = tid >> 5;
#pragma unroll
    for (int i = 0; i < 32; i += 8)
      tile[ty + i][tx] = W[(size_t)(k0 + ty + i) * N + n0 + tx];
    __syncthreads();
#pragma unroll
    for (int i = 0; i < 32; i += 8)
      Wt[(size_t)(n0 + ty + i) * K + k0 + tx] = (__bf16)tile[tx][ty + i];
  } else {
    // ---- LN1 job ----
    float* red = smem_f;
    const int row = bid - 8192;
    const float4 v = ((const float4*)(x + (size_t)row * D_DIM))[tid];
    float s = v.x + v.y + v.z + v.w;
#pragma unroll
    for (int off = 32; off >= 1; off >>= 1) s += __shfl_xor(s, off, 64);
    if ((tid & 63) == 0) red[tid >> 6] = s;
    __syncthreads();
    const float mean = (red[0] + red[1] + red[2] + red[3]) * (1.0f / D_DIM);
    const float d0 = v.x - mean, d1 = v.y - mean, d2 = v.z - mean, d3 = v.w - mean;
    float ss = d0 * d0 + d1 * d1 + d2 * d2 + d3 * d3;
#pragma unroll
    for (int off = 32; off >= 1; off >>= 1) ss += __shfl_xor(ss, off, 64);
    if ((tid & 63) == 0) red[4 + (tid >> 6)] = ss;
    __syncthreads();
    const float var = (red[4] + red[5] + red[6] + red[7]) * (1.0f / D_DIM);
    const float rstd = rsqrtf(var + 1e-5f);
    const float4 gg = ((const float4*)ng)[tid];
    const float4 bb = ((const float4*)nb)[tid];
    bf16x4 o;
    o[0] = (__bf16)(d0 * rstd * gg.x + bb.x);
    o[1] = (__bf16)(d1 * rstd * gg.y + bb.y);
    o[2] = (__bf16)(d2 * rstd * gg.z + bb.z);
    o[3] = (__bf16)(d3 * rstd * gg.w + bb.w);
    *(bf16x4*)(h + (size_t)row * D_DIM + tid * 4) = o;
  }
}

// ---------------------------------------------------------------------------
// LayerNorm (bf16 in) — LN2 only.
// ---------------------------------------------------------------------------
__global__ __launch_bounds__(256) void ln_kernel(
    const __bf16* __restrict__ x, const float* __restrict__ g,
    const float* __restrict__ b, __bf16* __restrict__ out) {
  __shared__ float red[8];
  const int row = blockIdx.x, tid = threadIdx.x;
  const bf16x4 v = ((const bf16x4*)(x + (size_t)row * D_DIM))[tid];
  const float v0 = (float)v[0], v1 = (float)v[1], v2 = (float)v[2], v3 = (float)v[3];
  float s = v0 + v1 + v2 + v3;
#pragma unroll
  for (int off = 32; off >= 1; off >>= 1) s += __shfl_xor(s, off, 64);
  if ((tid & 63) == 0) red[tid >> 6] = s;
  __syncthreads();
  const float mean = (red[0] + red[1] + red[2] + red[3]) * (1.0f / D_DIM);
  const float d0 = v0 - mean, d1 = v1 - mean, d2 = v2 - mean, d3 = v3 - mean;
  float ss = d0 * d0 + d1 * d1 + d2 * d2 + d3 * d3;
#pragma unroll
  for (int off = 32; off >= 1; off >>= 1) ss += __shfl_xor(ss, off, 64);
  if ((tid & 63) == 0) red[4 + (tid >> 6)] = ss;
  __syncthreads();
  const float var = (red[4] + red[5] + red[6] + red[7]) * (1.0f / D_DIM);
  const float rstd = rsqrtf(var + 1e-5f);
  const float4 gg = ((const float4*)g)[tid];
  const float4 bb = ((const float4*)b)[tid];
  bf16x4 o;
  o[0] = (__bf16)(d0 * rstd * gg.x + bb.x);
  o[1] = (__bf16)(d1 * rstd * gg.y + bb.y);
  o[2] = (__bf16)(d2 * rstd * gg.z + bb.z);
  o[3] = (__bf16)(d3 * rstd * gg.w + bb.w);
  *(bf16x4*)(out + (size_t)row * D_DIM + tid * 4) = o;
}

// ---------------------------------------------------------------------------
// gemm8 (R10-verified schedule) with optional DUAL job decode: blocks
// [0,split) run job 1 (params A..nbn), blocks [split,grid) run job 2
// (params A2..nbn2). Both jobs share BM_, EPI, K. Used to co-schedule the
// independent QK and V projections in one launch (3 blocks/CU).
// EPI: 0 bf16; 3 silu->bf16; 4 +Res(f32)->bf16; 5 +Res(bf16)->f32.
// ---------------------------------------------------------------------------
template <int BM_, int EPI, bool DUAL>
__global__ __launch_bounds__(512, 2) void gemm8(
    const __bf16* Ap, const __bf16* Btp, const void* Res, void* Coutp,
    int Mp, int Np, int K, int nbnp, int split,
    const __bf16* A2, const __bf16* Bt2, void* Cout2,
    int M2, int N2, int nbn2) {
  constexpr int MF = BM_ / 32;
  constexpr int MH = MF / 2;
  constexpr int SA = 8 * MF;
  constexpr int LA = BM_ / 128;
  constexpr int ATILE = BM_ * 64;
  constexpr int AHALF = BM_ * 32;
  constexpr int BOFF = 2 * ATILE;
  __shared__ __bf16 lds[2 * BM_ * 64 + 32768];

  const __bf16* A = Ap;
  const __bf16* Bt = Btp;
  void* Cout = Coutp;
  int M = Mp, N = Np, nbn = nbnp;
  int bid = (int)blockIdx.x;
  int nwg = gridDim.x;
  if constexpr (DUAL) {
    if (bid >= split) {
      A = A2; Bt = Bt2; Cout = Cout2; M = M2; N = N2; nbn = nbn2;
      bid -= split; nwg = gridDim.x - split;
    } else {
      nwg = split;
    }
  }
  (void)M;

  const int tid = threadIdx.x;
  const int l = tid & 63, w = tid >> 6;
  const int lr = l & 15, lg = l >> 4;
  const int wr = w >> 2, wc = w & 3;
  const int swz = (bid & 7) * (nwg >> 3) + (bid >> 3);
  const int bm = swz / nbn, bn = swz % nbn;
  const int am0 = bm * BM_, bn0 = bn * 256;

  f32x4 acc[MF][4];
  const f32x4 z4 = {0.f, 0.f, 0.f, 0.f};
#pragma unroll
  for (int m = 0; m < MF; ++m)
#pragma unroll
    for (int n = 0; n < 4; ++n) acc[m][n] = z4;

  auto stageA = [&](int h, int b, int k0) {
#pragma unroll
    for (int r = 0; r < LA; ++r) {
      const int ci = r * 512 + tid;
      const int wri = ci >> 3, c8 = ci & 7;
      const int ra = (wri % SA) + (wri / SA) * (2 * SA) + h * SA;
      gld_lds16(A + (size_t)(am0 + ra) * K + k0 + ((c8 ^ (wri & 7)) << 3),
                (__bf16*)lds + b * ATILE + h * AHALF + ci * 8);
    }
  };
  auto stageB = [&](int h, int b, int k0) {
#pragma unroll
    for (int r = 0; r < 2; ++r) {
      const int ci = r * 512 + tid;
      const int wri = ci >> 3, c8 = ci & 7;
      const int rb = (wri & 31) + (wri >> 5) * 64 + h * 32;
      gld_lds16(Bt + (size_t)(bn0 + rb) * K + k0 + ((c8 ^ (wri & 7)) << 3),
                (__bf16*)lds + BOFF + b * 16384 + h * 8192 + ci * 8);
    }
  };

  const int x7 = lr & 7;
  const int aoff0 = (lr + wr * SA) * 64 + ((lg) ^ x7) * 8;
  const int aoff1 = (lr + wr * SA) * 64 + ((4 + lg) ^ x7) * 8;
  const int boff0 = BOFF + (lr + wc * 32) * 64 + ((lg) ^ x7) * 8;
  const int boff1 = BOFF + (lr + wc * 32) * 64 + ((4 + lg) ^ x7) * 8;

  const int nt = K >> 6;
  stageA(0, 0, 0);
  stageB(1, 0, 0);
  stageB(0, 0, 0);
  stageA(1, 0, 0);
  stageA(0, 1, 64);
  stageB(1, 1, 64);
  if constexpr (BM_ == 256) VMCNT(6); else VMCNT(4);
  BAR();

  int buf = 0;
  bf16x8 afr[MH][2], bfr0[2][2], bfr1[2][2];
  for (int t = 0; t < nt; ++t) {
    const bool s1 = (t + 1 < nt);
    const bool s2 = (t + 2 < nt);
    const int nb_ = buf ^ 1;
    const int k1 = (t + 1) << 6;
    const int k2 = (t + 2) << 6;
    const __bf16* pa0 = lds + buf * ATILE + aoff0;
    const __bf16* pa1 = lds + buf * ATILE + aoff1;
    const __bf16* pb0 = lds + buf * 16384 + boff0;
    const __bf16* pb1 = lds + buf * 16384 + boff1;

    // ---- phase 1: read Ah0+Bh0; stage Bh0(t+1); MFMA q00 ----
#pragma unroll
    for (int i = 0; i < MH; ++i) {
      afr[i][0] = *(const bf16x8*)(pa0 + i * 1024);
      afr[i][1] = *(const bf16x8*)(pa1 + i * 1024);
    }
#pragma unroll
    for (int j = 0; j < 2; ++j) {
      bfr0[j][0] = *(const bf16x8*)(pb0 + j * 1024);
      bfr0[j][1] = *(const bf16x8*)(pb1 + j * 1024);
    }
    if (s1) stageB(0, nb_, k1);
    BAR();
    __builtin_amdgcn_s_setprio(1);
#pragma unroll
    for (int kk = 0; kk < 2; ++kk)
#pragma unroll
      for (int i = 0; i < MH; ++i)
#pragma unroll
        for (int j = 0; j < 2; ++j)
          acc[i][j] = MFMA16(afr[i][kk], bfr0[j][kk], acc[i][j]);
    __builtin_amdgcn_s_setprio(0);

    // ---- phase 2: read Bh1; stage Ah1(t+1); counted gate ----
#pragma unroll
    for (int j = 0; j < 2; ++j) {
      bfr1[j][0] = *(const bf16x8*)(pb0 + 8192 + j * 1024);
      bfr1[j][1] = *(const bf16x8*)(pb1 + 8192 + j * 1024);
    }
    if (s1) {
      stageA(1, nb_, k1);
      if constexpr (BM_ == 256) VMCNT(8); else VMCNT(6);
    } else {
      VMCNT(0);
    }
    BAR();
    __builtin_amdgcn_s_setprio(1);
#pragma unroll
    for (int kk = 0; kk < 2; ++kk)
#pragma unroll
      for (int i = 0; i < MH; ++i)
#pragma unroll
        for (int j = 0; j < 2; ++j)
          acc[i][2 + j] = MFMA16(afr[i][kk], bfr1[j][kk], acc[i][2 + j]);
    __builtin_amdgcn_s_setprio(0);

    // ---- phase 3: read Ah1; stage Ah0(t+2) into live buf ----
#pragma unroll
    for (int i = 0; i < MH; ++i) {
      afr[i][0] = *(const bf16x8*)(pa0 + AHALF + i * 1024);
      afr[i][1] = *(const bf16x8*)(pa1 + AHALF + i * 1024);
    }
    if (s2) stageA(0, buf, k2);
    BAR();
    __builtin_amdgcn_s_setprio(1);
#pragma unroll
    for (int kk = 0; kk < 2; ++kk)
#pragma unroll
      for (int i = 0; i < MH; ++i)
#pragma unroll
        for (int j = 0; j < 2; ++j)
          acc[MH + i][2 + j] = MFMA16(afr[i][kk], bfr1[j][kk], acc[MH + i][2 + j]);
    __builtin_amdgcn_s_setprio(0);

    // ---- phase 4: stage Bh1(t+2); counted gate ----
    if (s2) {
      stageB(1, buf, k2);
      if constexpr (BM_ == 256) VMCNT(6); else VMCNT(4);
    } else if (s1) {
      if constexpr (BM_ == 256) VMCNT(2); else VMCNT(1);
    }
    BAR();
    __builtin_amdgcn_s_setprio(1);
#pragma unroll
    for (int kk = 0; kk < 2; ++kk)
#pragma unroll
      for (int i = 0; i < MH; ++i)
#pragma unroll
        for (int j = 0; j < 2; ++j)
          acc[MH + i][j] = MFMA16(afr[i][kk], bfr0[j][kk], acc[MH + i][j]);
    __builtin_amdgcn_s_setprio(0);

    buf = nb_;
  }

  // ---- epilogue. C/D frag: col = lane&15, row = (lane>>4)*4 + reg ----
  if constexpr (EPI == 5) {
    const __bf16* R = (const __bf16*)Res;
    float* O = (float*)Cout;
#pragma unroll
    for (int mf = 0; mf < MF; ++mf)
#pragma unroll
      for (int nf = 0; nf < 4; ++nf)
#pragma unroll
        for (int r = 0; r < 4; ++r) {
          const int row = am0 + wr * 2 * SA + mf * 16 + lg * 4 + r;
          const int col = bn0 + wc * 64 + nf * 16 + lr;
          const size_t idx = (size_t)row * N + col;
          O[idx] = acc[mf][nf][r] + (float)R[idx];
        }
  } else {
    __syncthreads();
    __bf16* Ct = (__bf16*)lds;
#pragma unroll
    for (int mf = 0; mf < MF; ++mf)
#pragma unroll
      for (int nf = 0; nf < 4; ++nf)
#pragma unroll
        for (int r = 0; r < 4; ++r) {
          const int rl = wr * 2 * SA + mf * 16 + lg * 4 + r;
          const int cl = wc * 64 + nf * 16 + lr;
          float v = acc[mf][nf][r];
          if constexpr (EPI == 3) v = v / (1.f + __expf(-v));
          if constexpr (EPI == 4)
            v += ((const float*)Res)[(size_t)(am0 + rl) * N + bn0 + cl];
          Ct[rl * 256 + (((cl >> 3) ^ (rl & 7)) << 3) + (cl & 7)] = (__bf16)v;
        }
    __syncthreads();
    __bf16* O = (__bf16*)Cout;
#pragma unroll
    for (int i = 0; i < BM_ / 16; ++i) {
      const int ci = i * 512 + tid;
      const int row = ci >> 5, c8 = ci & 31;
      *(bf16x8*)(O + (size_t)(am0 + row) * N + bn0 + c8 * 8) =
          *(const bf16x8*)&Ct[row * 256 + ((c8 ^ (row & 7)) << 3)];
    }
  }
}

// ---------------------------------------------------------------------------
// Block-local attention v6 — one wave per block (R14-verified).
// ---------------------------------------------------------------------------
__global__ __launch_bounds__(64, 2) void attn_kernel(
    const __bf16* __restrict__ qk, const __bf16* __restrict__ vT,
    __bf16* __restrict__ out) {
  __shared__ __bf16 Pw[32 * 136];  // 8704 B

  const int l = (int)threadIdx.x;
  const int lr = l & 15, lg = l >> 4;
  const int bx = (int)blockIdx.x;
  const int swz = (bx & 7) * 512 + (bx >> 3);
  const int h = swz >> 8;
  const int blk = (swz >> 2) & 63;
  const int w = swz & 3;

  const __bf16* qbase =
      qk + (size_t)(blk * 128 + w * 32 + lr) * QKS + h * 64 + lg * 8;
  bf16x8 qf[2][2];
#pragma unroll
  for (int m = 0; m < 2; ++m)
#pragma unroll
    for (int ks = 0; ks < 2; ++ks)
      qf[m][ks] = *(const bf16x8*)(qbase + (size_t)m * 16 * QKS + ks * 32);

  const f32x4 z4 = {0.f, 0.f, 0.f, 0.f};
  float ssum[2][4];
  f32x4 o[2][4];
#pragma unroll
  for (int m = 0; m < 2; ++m) {
#pragma unroll
    for (int r = 0; r < 4; ++r) ssum[m][r] = 0.f;
#pragma unroll
    for (int n = 0; n < 4; ++n) o[m][n] = z4;
  }

  for (int it = 0; it < 3; ++it) {
    const int kb = blk + it - 1;
    if (kb < 0 || kb >= NB_DIM) continue;
    const int rel = it - 1;
    const int kclo = (rel < 0) ? (w * 2) : 0;
    const int kchi = (rel > 0) ? (w * 2 + 2) : 8;

    f32x4 s[2][8];
    const __bf16* kbase =
        qk + (size_t)(kb * 128 + lr) * QKS + 1024 + h * 64 + lg * 8;
#pragma unroll
    for (int kc = 0; kc < 8; ++kc) {
      if (kc < kclo || kc >= kchi) continue;
      const bf16x8 k0 = *(const bf16x8*)(kbase + (size_t)kc * 16 * QKS);
      const bf16x8 k1 = *(const bf16x8*)(kbase + (size_t)kc * 16 * QKS + 32);
      s[0][kc] = MFMA16(qf[0][0], k0, z4);
      s[1][kc] = MFMA16(qf[1][0], k0, z4);
      s[0][kc] = MFMA16(qf[0][1], k1, s[0][kc]);
      s[1][kc] = MFMA16(qf[1][1], k1, s[1][kc]);
    }

#pragma unroll
    for (int m = 0; m < 2; ++m) {
#pragma unroll
      for (int r = 0; r < 4; ++r) {
        const int qi = w * 32 + m * 16 + lg * 4 + r;
        float acc_s = 0.f;
#pragma unroll
        for (int kc = 0; kc < 8; ++kc) {
          if (kc < kclo || kc >= kchi) continue;
          const int kj = kc * 16 + lr;
          float p = __expf(s[m][kc][r] * 0.125f);
          const bool valid = (rel == 0) || (rel < 0 ? (kj >= qi) : (kj <= qi));
          p = valid ? p : 0.f;
          s[m][kc][r] = p;
          acc_s += p;
        }
        ssum[m][r] += acc_s;
      }
    }

#pragma unroll
    for (int m = 0; m < 2; ++m)
#pragma unroll
      for (int kc = 0; kc < 8; ++kc) {
        if (kc < kclo || kc >= kchi) continue;
#pragma unroll
        for (int r = 0; r < 4; ++r)
          Pw[(m * 16 + lg * 4 + r) * 136 + kc * 16 + lr] = (__bf16)s[m][kc][r];
      }

    const int kslo = kclo >> 1, kshi = kchi >> 1;
    const __bf16* vbase =
        vT + (size_t)(h * 64 + lr) * T_DIM + kb * 128 + lg * 8;
#pragma unroll
    for (int ks = 0; ks < 4; ++ks) {
      if (ks < kslo || ks >= kshi) continue;
      bf16x8 pa[2];
#pragma unroll
      for (int m = 0; m < 2; ++m)
        pa[m] = *(const bf16x8*)&Pw[(m * 16 + lr) * 136 + ks * 32 + lg * 8];
#pragma unroll
      for (int n = 0; n < 4; ++n) {
        const bf16x8 vb = *(const bf16x8*)(vbase + (size_t)n * 16 * T_DIM + ks * 32);
        o[0][n] = MFMA16(pa[0], vb, o[0][n]);
        o[1][n] = MFMA16(pa[1], vb, o[1][n]);
      }
    }
  }

  float inv[2][4];
#pragma unroll
  for (int m = 0; m < 2; ++m)
#pragma unroll
    for (int r = 0; r < 4; ++r) {
      float rs = ssum[m][r];
#pragma unroll
      for (int off = 1; off < 16; off <<= 1) rs += __shfl_xor(rs, off, 64);
      inv[m][r] = __builtin_amdgcn_rcpf(rs);
    }
#pragma unroll
  for (int m = 0; m < 2; ++m)
#pragma unroll
    for (int n = 0; n < 4; ++n)
#pragma unroll
      for (int r = 0; r < 4; ++r)
        Pw[(m * 16 + lg * 4 + r) * 136 + n * 16 + lr] =
            (__bf16)(o[m][n][r] * inv[m][r]);
#pragma unroll
  for (int i = 0; i < 4; ++i) {
    const int ci = i * 64 + l;
    const int qrow = ci >> 3;
    const int c8 = (ci & 7) * 8;
    const bf16x8 vv = *(const bf16x8*)&Pw[qrow * 136 + c8];
    *(bf16x8*)(out + (size_t)(blk * 128 + w * 32 + qrow) * D_DIM + h * 64 + c8) = vv;
  }
}

// ---------------------------------------------------------------------------
extern "C" void kernel_launch(void* const* d_in, const int* in_sizes, int n_in,
                              void* d_out, int out_size, void* d_ws, size_t ws_size,
                              hipStream_t stream) {
  (void)in_sizes; (void)n_in; (void)out_size; (void)ws_size;
  const float* x      = (const float*)d_in[0];
  const float* wq     = (const float*)d_in[1];
  const float* wk     = (const float*)d_in[2];
  const float* wv     = (const float*)d_in[3];
  const float* wo     = (const float*)d_in[4];
  const float* wg     = (const float*)d_in[5];
  const float* wd     = (const float*)d_in[6];
  const float* norm_g = (const float*)d_in[7];
  const float* norm_b = (const float*)d_in[8];
  const float* ffn_g  = (const float*)d_in[9];
  const float* ffn_b  = (const float*)d_in[10];
  float* out = (float*)d_out;

  // Workspace layout (96 MB used)
  char* ws = (char*)d_ws;
  constexpr size_t MB = 1ull << 20;
  __bf16* wqkT = (__bf16*)(ws + 0 * MB);    // [2048][1024]
  __bf16* wvT  = (__bf16*)(ws + 4 * MB);    // [1024][1024]
  __bf16* woT  = (__bf16*)(ws + 6 * MB);
  __bf16* wgT  = (__bf16*)(ws + 8 * MB);    // [2048][1024]
  __bf16* wdT  = (__bf16*)(ws + 12 * MB);   // [1024][2048]
  __bf16* hbuf = (__bf16*)(ws + 16 * MB);   // h / attn_out / h2 (16 MB, reused)
  __bf16* qkbf = (__bf16*)(ws + 32 * MB);   // [T][2048] fused q|k (32 MB)
  __bf16* gbf  = (__bf16*)(ws + 32 * MB);   // [T][2048] gate (reuses qk)
  __bf16* vTbf = (__bf16*)(ws + 64 * MB);   // [1024][T] (16 MB)
  __bf16* x2bf = (__bf16*)(ws + 80 * MB);   // [T][D] bf16 residual (16 MB)

  // 1. weight transposes + LN1 in ONE launch
  prep_all<<<16384, 256, 0, stream>>>(wq, wk, wv, wo, wg, wd,
                                      wqkT, wvT, woT, wgT, wdT,
                                      x, norm_g, norm_b, hbuf);

  // 2. QK projection (BM=128, 512 blocks) + V^T swapped-operand (256 blocks)
  //    co-scheduled in one DUAL launch: 768 blocks = 3/CU.
  gemm8<128, 0, true><<<768, 512, 0, stream>>>(
      hbuf, wqkT, nullptr, qkbf, 8192, 2048, 1024, 8, 512,
      wvT, hbuf, vTbf, 1024, 8192, 32);

  // 3. local attention -> hbuf (1 wave per block)
  attn_kernel<<<4096, 64, 0, stream>>>(qkbf, vTbf, hbuf);

  // 4. out-proj + residual: x2bf = bf16(x + attn @ wo)
  gemm8<128, 4, false><<<256, 512, 0, stream>>>(
      hbuf, woT, x, x2bf, 8192, 1024, 1024, 4, 0,
      nullptr, nullptr, nullptr, 0, 0, 1);

  // 5. LN2 (bf16 in) -> hbuf
  ln_kernel<<<8192, 256, 0, stream>>>(x2bf, ffn_g, ffn_b, hbuf);

  // 6. gate: g = silu(h2 @ wg)
  gemm8<256, 3, false><<<256, 512, 0, stream>>>(
      hbuf, wgT, nullptr, gbf, 8192, 2048, 1024, 8, 0,
      nullptr, nullptr, nullptr, 0, 0, 1);

  // 7. down + residual: out = f32(x2bf + g @ wd)
  gemm8<128, 5, false><<<256, 512, 0, stream>>>(
      gbf, wdT, x2bf, out, 8192, 1024, 2048, 4, 0,
      nullptr, nullptr, nullptr, 0, 0, 1);
}

// Round 17
// 232.382 us; speedup vs baseline: 1.0326x; 1.0215x over previous
//
#include <hip/hip_runtime.h>
#include <cstdint>

// Problem constants
#define T_DIM 8192
#define D_DIM 1024
#define NB_DIM 64
#define QKS 2048  // row stride of fused q|k buffer

typedef __bf16 bf16x8 __attribute__((ext_vector_type(8)));
typedef __bf16 bf16x4 __attribute__((ext_vector_type(4)));
typedef float f32x4 __attribute__((ext_vector_type(4)));

#define MFMA16(a, b, c) __builtin_amdgcn_mfma_f32_16x16x32_bf16((a), (b), (c), 0, 0, 0)
#define BAR() asm volatile("s_barrier" ::: "memory")
#define VMCNT(n) asm volatile("s_waitcnt vmcnt(" #n ")" ::: "memory")

// async global->LDS, 16B per lane. LDS dest must be wave-uniform base + lane*16.
__device__ __forceinline__ void gld_lds16(const void* gsrc, void* ldst) {
  __builtin_amdgcn_global_load_lds(
      (__attribute__((address_space(1))) void*)(uintptr_t)gsrc,
      (__attribute__((address_space(3))) void*)(uintptr_t)ldst,
      16, 0, 0);
}

// ---------------------------------------------------------------------------
// prep_all — weight transposes (blocks 0..8191) + LN1 (blocks 8192..16383).
// ---------------------------------------------------------------------------
__global__ __launch_bounds__(256) void prep_all(
    const float* __restrict__ wq, const float* __restrict__ wk,
    const float* __restrict__ wv, const float* __restrict__ wo,
    const float* __restrict__ wg, const float* __restrict__ wd,
    __bf16* __restrict__ wqkT, __bf16* __restrict__ wvT,
    __bf16* __restrict__ woT, __bf16* __restrict__ wgT,
    __bf16* __restrict__ wdT,
    const float* __restrict__ x, const float* __restrict__ ng,
    const float* __restrict__ nb, __bf16* __restrict__ h) {
  __shared__ float smem_f[32 * 33];
  const int bid = (int)blockIdx.x;
  const int tid = threadIdx.x;

  if (bid < 8192) {
    float (*tile)[33] = (float(*)[33])smem_f;
    const float* W; __bf16* Wt; int K, N, n0, k0, local;
    if (bid < 1024)      { W = wq; Wt = wqkT;            K = 1024; N = 1024; local = bid; }
    else if (bid < 2048) { W = wk; Wt = wqkT + 1048576;  K = 1024; N = 1024; local = bid - 1024; }
    else if (bid < 3072) { W = wv; Wt = wvT;             K = 1024; N = 1024; local = bid - 2048; }
    else if (bid < 4096) { W = wo; Wt = woT;             K = 1024; N = 1024; local = bid - 3072; }
    else if (bid < 6144) { W = wg; Wt = wgT;             K = 1024; N = 2048; local = bid - 4096; }
    else                 { W = wd; Wt = wdT;             K = 2048; N = 1024; local = bid - 6144; }
    if (N == 2048) { n0 = (local & 63) * 32; k0 = (local >> 6) * 32; }
    else           { n0 = (local & 31) * 32; k0 = (local >> 5) * 32; }
    const int tx = tid & 31, ty = tid >> 5;
#pragma unroll
    for (int i = 0; i < 32; i += 8)
      tile[ty + i][tx] = W[(size_t)(k0 + ty + i) * N + n0 + tx];
    __syncthreads();
#pragma unroll
    for (int i = 0; i < 32; i += 8)
      Wt[(size_t)(n0 + ty + i) * K + k0 + tx] = (__bf16)tile[tx][ty + i];
  } else {
    float* red = smem_f;
    const int row = bid - 8192;
    const float4 v = ((const float4*)(x + (size_t)row * D_DIM))[tid];
    float s = v.x + v.y + v.z + v.w;
#pragma unroll
    for (int off = 32; off >= 1; off >>= 1) s += __shfl_xor(s, off, 64);
    if ((tid & 63) == 0) red[tid >> 6] = s;
    __syncthreads();
    const float mean = (red[0] + red[1] + red[2] + red[3]) * (1.0f / D_DIM);
    const float d0 = v.x - mean, d1 = v.y - mean, d2 = v.z - mean, d3 = v.w - mean;
    float ss = d0 * d0 + d1 * d1 + d2 * d2 + d3 * d3;
#pragma unroll
    for (int off = 32; off >= 1; off >>= 1) ss += __shfl_xor(ss, off, 64);
    if ((tid & 63) == 0) red[4 + (tid >> 6)] = ss;
    __syncthreads();
    const float var = (red[4] + red[5] + red[6] + red[7]) * (1.0f / D_DIM);
    const float rstd = rsqrtf(var + 1e-5f);
    const float4 gg = ((const float4*)ng)[tid];
    const float4 bb = ((const float4*)nb)[tid];
    bf16x4 o;
    o[0] = (__bf16)(d0 * rstd * gg.x + bb.x);
    o[1] = (__bf16)(d1 * rstd * gg.y + bb.y);
    o[2] = (__bf16)(d2 * rstd * gg.z + bb.z);
    o[3] = (__bf16)(d3 * rstd * gg.w + bb.w);
    *(bf16x4*)(h + (size_t)row * D_DIM + tid * 4) = o;
  }
}

// ---------------------------------------------------------------------------
// LayerNorm (bf16 in) — LN2 only.
// ---------------------------------------------------------------------------
__global__ __launch_bounds__(256) void ln_kernel(
    const __bf16* __restrict__ x, const float* __restrict__ g,
    const float* __restrict__ b, __bf16* __restrict__ out) {
  __shared__ float red[8];
  const int row = blockIdx.x, tid = threadIdx.x;
  const bf16x4 v = ((const bf16x4*)(x + (size_t)row * D_DIM))[tid];
  const float v0 = (float)v[0], v1 = (float)v[1], v2 = (float)v[2], v3 = (float)v[3];
  float s = v0 + v1 + v2 + v3;
#pragma unroll
  for (int off = 32; off >= 1; off >>= 1) s += __shfl_xor(s, off, 64);
  if ((tid & 63) == 0) red[tid >> 6] = s;
  __syncthreads();
  const float mean = (red[0] + red[1] + red[2] + red[3]) * (1.0f / D_DIM);
  const float d0 = v0 - mean, d1 = v1 - mean, d2 = v2 - mean, d3 = v3 - mean;
  float ss = d0 * d0 + d1 * d1 + d2 * d2 + d3 * d3;
#pragma unroll
  for (int off = 32; off >= 1; off >>= 1) ss += __shfl_xor(ss, off, 64);
  if ((tid & 63) == 0) red[4 + (tid >> 6)] = ss;
  __syncthreads();
  const float var = (red[4] + red[5] + red[6] + red[7]) * (1.0f / D_DIM);
  const float rstd = rsqrtf(var + 1e-5f);
  const float4 gg = ((const float4*)g)[tid];
  const float4 bb = ((const float4*)b)[tid];
  bf16x4 o;
  o[0] = (__bf16)(d0 * rstd * gg.x + bb.x);
  o[1] = (__bf16)(d1 * rstd * gg.y + bb.y);
  o[2] = (__bf16)(d2 * rstd * gg.z + bb.z);
  o[3] = (__bf16)(d3 * rstd * gg.w + bb.w);
  *(bf16x4*)(out + (size_t)row * D_DIM + tid * 4) = o;
}

// ---------------------------------------------------------------------------
// gemm8 (R10-verified schedule) with optional DUAL job decode.
// EPI: 0 bf16; 3 silu->bf16; 4 +Res(f32)->bf16; 5 +Res(bf16)->f32.
// ---------------------------------------------------------------------------
template <int BM_, int EPI, bool DUAL>
__global__ __launch_bounds__(512, 2) void gemm8(
    const __bf16* Ap, const __bf16* Btp, const void* Res, void* Coutp,
    int Mp, int Np, int K, int nbnp, int split,
    const __bf16* A2, const __bf16* Bt2, void* Cout2,
    int M2, int N2, int nbn2) {
  constexpr int MF = BM_ / 32;
  constexpr int MH = MF / 2;
  constexpr int SA = 8 * MF;
  constexpr int LA = BM_ / 128;
  constexpr int ATILE = BM_ * 64;
  constexpr int AHALF = BM_ * 32;
  constexpr int BOFF = 2 * ATILE;
  __shared__ __bf16 lds[2 * BM_ * 64 + 32768];

  const __bf16* A = Ap;
  const __bf16* Bt = Btp;
  void* Cout = Coutp;
  int M = Mp, N = Np, nbn = nbnp;
  int bid = (int)blockIdx.x;
  int nwg = gridDim.x;
  if constexpr (DUAL) {
    if (bid >= split) {
      A = A2; Bt = Bt2; Cout = Cout2; M = M2; N = N2; nbn = nbn2;
      bid -= split; nwg = gridDim.x - split;
    } else {
      nwg = split;
    }
  }
  (void)M;

  const int tid = threadIdx.x;
  const int l = tid & 63, w = tid >> 6;
  const int lr = l & 15, lg = l >> 4;
  const int wr = w >> 2, wc = w & 3;
  const int swz = (bid & 7) * (nwg >> 3) + (bid >> 3);
  const int bm = swz / nbn, bn = swz % nbn;
  const int am0 = bm * BM_, bn0 = bn * 256;

  f32x4 acc[MF][4];
  const f32x4 z4 = {0.f, 0.f, 0.f, 0.f};
#pragma unroll
  for (int m = 0; m < MF; ++m)
#pragma unroll
    for (int n = 0; n < 4; ++n) acc[m][n] = z4;

  auto stageA = [&](int h, int b, int k0) {
#pragma unroll
    for (int r = 0; r < LA; ++r) {
      const int ci = r * 512 + tid;
      const int wri = ci >> 3, c8 = ci & 7;
      const int ra = (wri % SA) + (wri / SA) * (2 * SA) + h * SA;
      gld_lds16(A + (size_t)(am0 + ra) * K + k0 + ((c8 ^ (wri & 7)) << 3),
                (__bf16*)lds + b * ATILE + h * AHALF + ci * 8);
    }
  };
  auto stageB = [&](int h, int b, int k0) {
#pragma unroll
    for (int r = 0; r < 2; ++r) {
      const int ci = r * 512 + tid;
      const int wri = ci >> 3, c8 = ci & 7;
      const int rb = (wri & 31) + (wri >> 5) * 64 + h * 32;
      gld_lds16(Bt + (size_t)(bn0 + rb) * K + k0 + ((c8 ^ (wri & 7)) << 3),
                (__bf16*)lds + BOFF + b * 16384 + h * 8192 + ci * 8);
    }
  };

  const int x7 = lr & 7;
  const int aoff0 = (lr + wr * SA) * 64 + ((lg) ^ x7) * 8;
  const int aoff1 = (lr + wr * SA) * 64 + ((4 + lg) ^ x7) * 8;
  const int boff0 = BOFF + (lr + wc * 32) * 64 + ((lg) ^ x7) * 8;
  const int boff1 = BOFF + (lr + wc * 32) * 64 + ((4 + lg) ^ x7) * 8;

  const int nt = K >> 6;
  stageA(0, 0, 0);
  stageB(1, 0, 0);
  stageB(0, 0, 0);
  stageA(1, 0, 0);
  stageA(0, 1, 64);
  stageB(1, 1, 64);
  if constexpr (BM_ == 256) VMCNT(6); else VMCNT(4);
  BAR();

  int buf = 0;
  bf16x8 afr[MH][2], bfr0[2][2], bfr1[2][2];
  for (int t = 0; t < nt; ++t) {
    const bool s1 = (t + 1 < nt);
    const bool s2 = (t + 2 < nt);
    const int nb_ = buf ^ 1;
    const int k1 = (t + 1) << 6;
    const int k2 = (t + 2) << 6;
    const __bf16* pa0 = lds + buf * ATILE + aoff0;
    const __bf16* pa1 = lds + buf * ATILE + aoff1;
    const __bf16* pb0 = lds + buf * 16384 + boff0;
    const __bf16* pb1 = lds + buf * 16384 + boff1;

    // ---- phase 1: read Ah0+Bh0; stage Bh0(t+1); MFMA q00 ----
#pragma unroll
    for (int i = 0; i < MH; ++i) {
      afr[i][0] = *(const bf16x8*)(pa0 + i * 1024);
      afr[i][1] = *(const bf16x8*)(pa1 + i * 1024);
    }
#pragma unroll
    for (int j = 0; j < 2; ++j) {
      bfr0[j][0] = *(const bf16x8*)(pb0 + j * 1024);
      bfr0[j][1] = *(const bf16x8*)(pb1 + j * 1024);
    }
    if (s1) stageB(0, nb_, k1);
    BAR();
    __builtin_amdgcn_s_setprio(1);
#pragma unroll
    for (int kk = 0; kk < 2; ++kk)
#pragma unroll
      for (int i = 0; i < MH; ++i)
#pragma unroll
        for (int j = 0; j < 2; ++j)
          acc[i][j] = MFMA16(afr[i][kk], bfr0[j][kk], acc[i][j]);
    __builtin_amdgcn_s_setprio(0);

    // ---- phase 2: read Bh1; stage Ah1(t+1); counted gate ----
#pragma unroll
    for (int j = 0; j < 2; ++j) {
      bfr1[j][0] = *(const bf16x8*)(pb0 + 8192 + j * 1024);
      bfr1[j][1] = *(const bf16x8*)(pb1 + 8192 + j * 1024);
    }
    if (s1) {
      stageA(1, nb_, k1);
      if constexpr (BM_ == 256) VMCNT(8); else VMCNT(6);
    } else {
      VMCNT(0);
    }
    BAR();
    __builtin_amdgcn_s_setprio(1);
#pragma unroll
    for (int kk = 0; kk < 2; ++kk)
#pragma unroll
      for (int i = 0; i < MH; ++i)
#pragma unroll
        for (int j = 0; j < 2; ++j)
          acc[i][2 + j] = MFMA16(afr[i][kk], bfr1[j][kk], acc[i][2 + j]);
    __builtin_amdgcn_s_setprio(0);

    // ---- phase 3: read Ah1; stage Ah0(t+2) into live buf ----
#pragma unroll
    for (int i = 0; i < MH; ++i) {
      afr[i][0] = *(const bf16x8*)(pa0 + AHALF + i * 1024);
      afr[i][1] = *(const bf16x8*)(pa1 + AHALF + i * 1024);
    }
    if (s2) stageA(0, buf, k2);
    BAR();
    __builtin_amdgcn_s_setprio(1);
#pragma unroll
    for (int kk = 0; kk < 2; ++kk)
#pragma unroll
      for (int i = 0; i < MH; ++i)
#pragma unroll
        for (int j = 0; j < 2; ++j)
          acc[MH + i][2 + j] = MFMA16(afr[i][kk], bfr1[j][kk], acc[MH + i][2 + j]);
    __builtin_amdgcn_s_setprio(0);

    // ---- phase 4: stage Bh1(t+2); counted gate ----
    if (s2) {
      stageB(1, buf, k2);
      if constexpr (BM_ == 256) VMCNT(6); else VMCNT(4);
    } else if (s1) {
      if constexpr (BM_ == 256) VMCNT(2); else VMCNT(1);
    }
    BAR();
    __builtin_amdgcn_s_setprio(1);
#pragma unroll
    for (int kk = 0; kk < 2; ++kk)
#pragma unroll
      for (int i = 0; i < MH; ++i)
#pragma unroll
        for (int j = 0; j < 2; ++j)
          acc[MH + i][j] = MFMA16(afr[i][kk], bfr0[j][kk], acc[MH + i][j]);
    __builtin_amdgcn_s_setprio(0);

    buf = nb_;
  }

  // ---- epilogue. C/D frag: col = lane&15, row = (lane>>4)*4 + reg ----
  if constexpr (EPI == 5) {
    const __bf16* R = (const __bf16*)Res;
    float* O = (float*)Cout;
#pragma unroll
    for (int mf = 0; mf < MF; ++mf)
#pragma unroll
      for (int nf = 0; nf < 4; ++nf)
#pragma unroll
        for (int r = 0; r < 4; ++r) {
          const int row = am0 + wr * 2 * SA + mf * 16 + lg * 4 + r;
          const int col = bn0 + wc * 64 + nf * 16 + lr;
          const size_t idx = (size_t)row * N + col;
          O[idx] = acc[mf][nf][r] + (float)R[idx];
        }
  } else {
    __syncthreads();
    __bf16* Ct = (__bf16*)lds;
#pragma unroll
    for (int mf = 0; mf < MF; ++mf)
#pragma unroll
      for (int nf = 0; nf < 4; ++nf)
#pragma unroll
        for (int r = 0; r < 4; ++r) {
          const int rl = wr * 2 * SA + mf * 16 + lg * 4 + r;
          const int cl = wc * 64 + nf * 16 + lr;
          float v = acc[mf][nf][r];
          if constexpr (EPI == 3) v = v / (1.f + __expf(-v));
          if constexpr (EPI == 4)
            v += ((const float*)Res)[(size_t)(am0 + rl) * N + bn0 + cl];
          Ct[rl * 256 + (((cl >> 3) ^ (rl & 7)) << 3) + (cl & 7)] = (__bf16)v;
        }
    __syncthreads();
    __bf16* O = (__bf16*)Cout;
#pragma unroll
    for (int i = 0; i < BM_ / 16; ++i) {
      const int ci = i * 512 + tid;
      const int row = ci >> 5, c8 = ci & 31;
      *(bf16x8*)(O + (size_t)(am0 + row) * N + bn0 + c8 * 8) =
          *(const bf16x8*)&Ct[row * 256 + ((c8 ^ (row & 7)) << 3)];
    }
  }
}

// ---------------------------------------------------------------------------
// attention v7 — peeled tiles for cross-tile ILP. One wave per block.
// attn_tile<REL> handles one kb-block with REL constexpr (mask folds).
// The middle tile's K frags are prefetched at the top (overlap with Q loads);
// straight-line peeling lets the compiler hoist side-tile loads under the
// previous tile's exp chain.
// ---------------------------------------------------------------------------
template <int REL>
__device__ __forceinline__ void attn_tile(
    const __bf16* __restrict__ qk, const __bf16* __restrict__ vT,
    __bf16* Pw, const bf16x8 (&qf)[2][2], float (&ssum)[2][4],
    f32x4 (&o)[2][4], int kb, int h, int w, int lr, int lg) {
  const f32x4 z4 = {0.f, 0.f, 0.f, 0.f};
  const int kclo = (REL < 0) ? (w * 2) : 0;
  const int kchi = (REL > 0) ? (w * 2 + 2) : 8;

  f32x4 s[2][8];
  const __bf16* kbase = qk + (size_t)(kb * 128 + lr) * QKS + 1024 + h * 64 + lg * 8;
#pragma unroll
  for (int kc = 0; kc < 8; ++kc) {
    if (kc < kclo || kc >= kchi) continue;
    const bf16x8 k0 = *(const bf16x8*)(kbase + (size_t)kc * 16 * QKS);
    const bf16x8 k1 = *(const bf16x8*)(kbase + (size_t)kc * 16 * QKS + 32);
    s[0][kc] = MFMA16(qf[0][0], k0, z4);
    s[1][kc] = MFMA16(qf[1][0], k0, z4);
    s[0][kc] = MFMA16(qf[0][1], k1, s[0][kc]);
    s[1][kc] = MFMA16(qf[1][1], k1, s[1][kc]);
  }

#pragma unroll
  for (int m = 0; m < 2; ++m) {
#pragma unroll
    for (int r = 0; r < 4; ++r) {
      const int qi = w * 32 + m * 16 + lg * 4 + r;
      float acc_s = 0.f;
#pragma unroll
      for (int kc = 0; kc < 8; ++kc) {
        if (kc < kclo || kc >= kchi) continue;
        const int kj = kc * 16 + lr;
        float p = __expf(s[m][kc][r] * 0.125f);
        const bool valid = (REL == 0) || (REL < 0 ? (kj >= qi) : (kj <= qi));
        p = valid ? p : 0.f;
        s[m][kc][r] = p;
        acc_s += p;
      }
      ssum[m][r] += acc_s;
    }
  }

#pragma unroll
  for (int m = 0; m < 2; ++m)
#pragma unroll
    for (int kc = 0; kc < 8; ++kc) {
      if (kc < kclo || kc >= kchi) continue;
#pragma unroll
      for (int r = 0; r < 4; ++r)
        Pw[(m * 16 + lg * 4 + r) * 136 + kc * 16 + lr] = (__bf16)s[m][kc][r];
    }

  const int kslo = kclo >> 1, kshi = kchi >> 1;
  const __bf16* vbase = vT + (size_t)(h * 64 + lr) * T_DIM + kb * 128 + lg * 8;
#pragma unroll
  for (int ks = 0; ks < 4; ++ks) {
    if (ks < kslo || ks >= kshi) continue;
    bf16x8 pa[2];
#pragma unroll
    for (int m = 0; m < 2; ++m)
      pa[m] = *(const bf16x8*)&Pw[(m * 16 + lr) * 136 + ks * 32 + lg * 8];
#pragma unroll
    for (int n = 0; n < 4; ++n) {
      const bf16x8 vb = *(const bf16x8*)(vbase + (size_t)n * 16 * T_DIM + ks * 32);
      o[0][n] = MFMA16(pa[0], vb, o[0][n]);
      o[1][n] = MFMA16(pa[1], vb, o[1][n]);
    }
  }
}

__global__ __launch_bounds__(64, 2) void attn_kernel(
    const __bf16* __restrict__ qk, const __bf16* __restrict__ vT,
    __bf16* __restrict__ out) {
  __shared__ __bf16 Pw[32 * 136];  // 8704 B

  const int l = (int)threadIdx.x;
  const int lr = l & 15, lg = l >> 4;
  const int bx = (int)blockIdx.x;
  const int swz = (bx & 7) * 512 + (bx >> 3);
  const int h = swz >> 8;
  const int blk = (swz >> 2) & 63;
  const int w = swz & 3;

  // ---- prefetch Q and middle-tile K concurrently ----
  const __bf16* qbase =
      qk + (size_t)(blk * 128 + w * 32 + lr) * QKS + h * 64 + lg * 8;
  bf16x8 qf[2][2];
#pragma unroll
  for (int m = 0; m < 2; ++m)
#pragma unroll
    for (int ks = 0; ks < 2; ++ks)
      qf[m][ks] = *(const bf16x8*)(qbase + (size_t)m * 16 * QKS + ks * 32);

  bf16x8 kf0[8][2];
  {
    const __bf16* kbase =
        qk + (size_t)(blk * 128 + lr) * QKS + 1024 + h * 64 + lg * 8;
#pragma unroll
    for (int kc = 0; kc < 8; ++kc) {
      kf0[kc][0] = *(const bf16x8*)(kbase + (size_t)kc * 16 * QKS);
      kf0[kc][1] = *(const bf16x8*)(kbase + (size_t)kc * 16 * QKS + 32);
    }
  }

  const f32x4 z4 = {0.f, 0.f, 0.f, 0.f};
  float ssum[2][4];
  f32x4 o[2][4];
#pragma unroll
  for (int m = 0; m < 2; ++m) {
#pragma unroll
    for (int r = 0; r < 4; ++r) ssum[m][r] = 0.f;
#pragma unroll
    for (int n = 0; n < 4; ++n) o[m][n] = z4;
  }

  // ---- middle tile (REL=0) inline, using prefetched K ----
  {
    f32x4 s[2][8];
#pragma unroll
    for (int kc = 0; kc < 8; ++kc) {
      s[0][kc] = MFMA16(qf[0][0], kf0[kc][0], z4);
      s[1][kc] = MFMA16(qf[1][0], kf0[kc][0], z4);
      s[0][kc] = MFMA16(qf[0][1], kf0[kc][1], s[0][kc]);
      s[1][kc] = MFMA16(qf[1][1], kf0[kc][1], s[1][kc]);
    }
#pragma unroll
    for (int m = 0; m < 2; ++m)
#pragma unroll
      for (int r = 0; r < 4; ++r) {
        float acc_s = 0.f;
#pragma unroll
        for (int kc = 0; kc < 8; ++kc) {
          const float p = __expf(s[m][kc][r] * 0.125f);
          s[m][kc][r] = p;
          acc_s += p;
        }
        ssum[m][r] += acc_s;
      }
#pragma unroll
    for (int m = 0; m < 2; ++m)
#pragma unroll
      for (int kc = 0; kc < 8; ++kc)
#pragma unroll
        for (int r = 0; r < 4; ++r)
          Pw[(m * 16 + lg * 4 + r) * 136 + kc * 16 + lr] = (__bf16)s[m][kc][r];
    const __bf16* vbase =
        vT + (size_t)(h * 64 + lr) * T_DIM + blk * 128 + lg * 8;
#pragma unroll
    for (int ks = 0; ks < 4; ++ks) {
      bf16x8 pa[2];
#pragma unroll
      for (int m = 0; m < 2; ++m)
        pa[m] = *(const bf16x8*)&Pw[(m * 16 + lr) * 136 + ks * 32 + lg * 8];
#pragma unroll
      for (int n = 0; n < 4; ++n) {
        const bf16x8 vb = *(const bf16x8*)(vbase + (size_t)n * 16 * T_DIM + ks * 32);
        o[0][n] = MFMA16(pa[0], vb, o[0][n]);
        o[1][n] = MFMA16(pa[1], vb, o[1][n]);
      }
    }
  }

  // ---- side tiles, peeled (straight-line: loads hoistable) ----
  if (blk > 0)
    attn_tile<-1>(qk, vT, Pw, qf, ssum, o, blk - 1, h, w, lr, lg);
  if (blk < NB_DIM - 1)
    attn_tile<1>(qk, vT, Pw, qf, ssum, o, blk + 1, h, w, lr, lg);

  // ---- finalize ----
  float inv[2][4];
#pragma unroll
  for (int m = 0; m < 2; ++m)
#pragma unroll
    for (int r = 0; r < 4; ++r) {
      float rs = ssum[m][r];
#pragma unroll
      for (int off = 1; off < 16; off <<= 1) rs += __shfl_xor(rs, off, 64);
      inv[m][r] = __builtin_amdgcn_rcpf(rs);
    }
#pragma unroll
  for (int m = 0; m < 2; ++m)
#pragma unroll
    for (int n = 0; n < 4; ++n)
#pragma unroll
      for (int r = 0; r < 4; ++r)
        Pw[(m * 16 + lg * 4 + r) * 136 + n * 16 + lr] =
            (__bf16)(o[m][n][r] * inv[m][r]);
#pragma unroll
  for (int i = 0; i < 4; ++i) {
    const int ci = i * 64 + l;
    const int qrow = ci >> 3;
    const int c8 = (ci & 7) * 8;
    const bf16x8 vv = *(const bf16x8*)&Pw[qrow * 136 + c8];
    *(bf16x8*)(out + (size_t)(blk * 128 + w * 32 + qrow) * D_DIM + h * 64 + c8) = vv;
  }
}

// ---------------------------------------------------------------------------
extern "C" void kernel_launch(void* const* d_in, const int* in_sizes, int n_in,
                              void* d_out, int out_size, void* d_ws, size_t ws_size,
                              hipStream_t stream) {
  (void)in_sizes; (void)n_in; (void)out_size; (void)ws_size;
  const float* x      = (const float*)d_in[0];
  const float* wq     = (const float*)d_in[1];
  const float* wk     = (const float*)d_in[2];
  const float* wv     = (const float*)d_in[3];
  const float* wo     = (const float*)d_in[4];
  const float* wg     = (const float*)d_in[5];
  const float* wd     = (const float*)d_in[6];
  const float* norm_g = (const float*)d_in[7];
  const float* norm_b = (const float*)d_in[8];
  const float* ffn_g  = (const float*)d_in[9];
  const float* ffn_b  = (const float*)d_in[10];
  float* out = (float*)d_out;

  // Workspace layout (96 MB used)
  char* ws = (char*)d_ws;
  constexpr size_t MB = 1ull << 20;
  __bf16* wqkT = (__bf16*)(ws + 0 * MB);    // [2048][1024]
  __bf16* wvT  = (__bf16*)(ws + 4 * MB);    // [1024][1024]
  __bf16* woT  = (__bf16*)(ws + 6 * MB);
  __bf16* wgT  = (__bf16*)(ws + 8 * MB);    // [2048][1024]
  __bf16* wdT  = (__bf16*)(ws + 12 * MB);   // [1024][2048]
  __bf16* hbuf = (__bf16*)(ws + 16 * MB);   // h / attn_out / h2 (16 MB, reused)
  __bf16* qkbf = (__bf16*)(ws + 32 * MB);   // [T][2048] fused q|k (32 MB)
  __bf16* gbf  = (__bf16*)(ws + 32 * MB);   // [T][2048] gate (reuses qk)
  __bf16* vTbf = (__bf16*)(ws + 64 * MB);   // [1024][T] (16 MB)
  __bf16* x2bf = (__bf16*)(ws + 80 * MB);   // [T][D] bf16 residual (16 MB)

  // 1. weight transposes + LN1 in ONE launch
  prep_all<<<16384, 256, 0, stream>>>(wq, wk, wv, wo, wg, wd,
                                      wqkT, wvT, woT, wgT, wdT,
                                      x, norm_g, norm_b, hbuf);

  // 2. QK projection + V^T swapped-operand, DUAL launch (3 blocks/CU)
  gemm8<128, 0, true><<<768, 512, 0, stream>>>(
      hbuf, wqkT, nullptr, qkbf, 8192, 2048, 1024, 8, 512,
      wvT, hbuf, vTbf, 1024, 8192, 32);

  // 3. local attention -> hbuf (1 wave per block, peeled tiles)
  attn_kernel<<<4096, 64, 0, stream>>>(qkbf, vTbf, hbuf);

  // 4. out-proj + residual: x2bf = bf16(x + attn @ wo)
  gemm8<128, 4, false><<<256, 512, 0, stream>>>(
      hbuf, woT, x, x2bf, 8192, 1024, 1024, 4, 0,
      nullptr, nullptr, nullptr, 0, 0, 1);

  // 5. LN2 (bf16 in) -> hbuf
  ln_kernel<<<8192, 256, 0, stream>>>(x2bf, ffn_g, ffn_b, hbuf);

  // 6. gate: g = silu(h2 @ wg)
  gemm8<256, 3, false><<<256, 512, 0, stream>>>(
      hbuf, wgT, nullptr, gbf, 8192, 2048, 1024, 8, 0,
      nullptr, nullptr, nullptr, 0, 0, 1);

  // 7. down + residual: out = f32(x2bf + g @ wd)
  gemm8<128, 5, false><<<256, 512, 0, stream>>>(
      gbf, wdT, x2bf, out, 8192, 1024, 2048, 4, 0,
      nullptr, nullptr, nullptr, 0, 0, 1);
}